// Round 9
// baseline (72.941 us; speedup 1.0000x reference)
//
#include <hip/hip_runtime.h>

#define BATCH 16
#define TOK   4096
#define DIM   768
#define SMAX  128
#define BM    8     // rows per MLP block

__device__ __forceinline__ int lower_bound_i(const int* __restrict__ a, int n, int v) {
    int lo = 0, hi = n;
    while (lo < hi) {
        int m = (lo + hi) >> 1;
        if (a[m] < v) lo = m + 1; else hi = m;
    }
    return lo;
}

__device__ __forceinline__ float f4get(const float4& v, int k) {
    switch (k) {
        case 0: return v.x;
        case 1: return v.y;
        case 2: return v.z;
        default: return v.w;
    }
}

__device__ __forceinline__ void f4acc(float4& a, const float4& v) {
    a.x += v.x; a.y += v.y; a.z += v.z; a.w += v.w;
}

// Kernel 0: precompute span boundaries. 16 blocks x 192 threads; thread s
// binary-searches seg[b] for s (0..128). Independent chains, fully parallel.
__global__ __launch_bounds__(192)
void bounds_kernel(const int* __restrict__ seg, int* __restrict__ bounds) {
    const int b = blockIdx.x;
    const int s = threadIdx.x;
    if (s <= SMAX)
        bounds[b * (SMAX + 1) + s] = lower_bound_i(seg + b * TOK, TOK, s);
}

// Kernel A: per-(b,s) segment sum over contiguous sorted token span.
// Span limits come precomputed from bounds_kernel (no dependent-load chain).
__global__ __launch_bounds__(192)
void segsum_kernel(const float* __restrict__ hidden,
                   const int* __restrict__ bounds,
                   float* __restrict__ sent) {
    const int s = blockIdx.x;
    const int b = blockIdx.y;
    const int tid = threadIdx.x;

    const int lo = bounds[b * (SMAX + 1) + s];
    const int hi = bounds[b * (SMAX + 1) + s + 1];

    const float4* __restrict__ hp =
        reinterpret_cast<const float4*>(hidden + (size_t)b * TOK * DIM) + tid;

    float4 acc = make_float4(0.f, 0.f, 0.f, 0.f);
    int t = lo;

    for (; t + 16 <= hi; t += 16) {
        float4 v[16];
        #pragma unroll
        for (int u = 0; u < 16; ++u)
            v[u] = hp[(size_t)(t + u) * (DIM / 4)];
        #pragma unroll
        for (int u = 0; u < 16; ++u)
            f4acc(acc, v[u]);
    }
    for (; t + 4 <= hi; t += 4) {
        float4 v[4];
        #pragma unroll
        for (int u = 0; u < 4; ++u)
            v[u] = hp[(size_t)(t + u) * (DIM / 4)];
        #pragma unroll
        for (int u = 0; u < 4; ++u)
            f4acc(acc, v[u]);
    }
    for (; t < hi; ++t)
        f4acc(acc, hp[(size_t)t * (DIM / 4)]);

    float4* outp = reinterpret_cast<float4*>(sent + (size_t)(b * SMAX + s) * DIM);
    outp[tid] = acc;
}

// Kernel B: fused MLP, BM=8 rows/block, 1024 threads (16 waves = 4/SIMD).
// k-split across 8 wave-pair groups; weights read exactly once per block.
// launch_bounds relaxed to 1024 (VGPR cap 128, still 1 block/CU) to kill spills.
__global__ __launch_bounds__(1024)
void mlp_kernel(const float* __restrict__ sent,
                const float* __restrict__ W1, const float* __restrict__ b1,
                const float* __restrict__ W2, const float* __restrict__ b2,
                const float* __restrict__ W3, const float* __restrict__ b3,
                float* __restrict__ out) {
    __shared__ __align__(16) float A [BM * DIM];        // 24 KB
    __shared__ __align__(16) float X1[BM * 384];        // 12 KB
    __shared__ __align__(16) float X2[BM * 128];        //  4 KB
    __shared__ __align__(16) float P [8 * BM * 384];    // 96 KB (P1; reused as P2)

    const int tid  = threadIdx.x;
    const int row0 = blockIdx.x * BM;
    const int c1   = tid & 127;   // weight column within 128-group
    const int kg   = tid >> 7;    // k-slice group 0..7 (uniform per wave)

    // ---- stage A tile ----
    {
        const float4* sA = reinterpret_cast<const float4*>(sent + (size_t)row0 * DIM);
        float4* dA = reinterpret_cast<float4*>(A);
        for (int i = tid; i < BM * DIM / 4; i += 1024)
            dA[i] = sA[i];
    }
    __syncthreads();

    // ---- layer 1: cols {c1, c1+128, c1+256}, rows 0..7, k in [kg*96, kg*96+96) ----
    {
        float acc[BM][3];
        #pragma unroll
        for (int r = 0; r < BM; ++r)
            #pragma unroll
            for (int j = 0; j < 3; ++j) acc[r][j] = 0.f;

        const int k0 = kg * 96;
        for (int k = k0; k < k0 + 96; k += 4) {
            float4 a[BM];
            #pragma unroll
            for (int r = 0; r < BM; ++r)
                a[r] = *reinterpret_cast<const float4*>(&A[r * DIM + k]);
            #pragma unroll
            for (int kk = 0; kk < 4; ++kk) {
                const float w0 = W1[(size_t)(k + kk) * 384 + c1];
                const float w1 = W1[(size_t)(k + kk) * 384 + c1 + 128];
                const float w2 = W1[(size_t)(k + kk) * 384 + c1 + 256];
                #pragma unroll
                for (int r = 0; r < BM; ++r) {
                    const float av = f4get(a[r], kk);
                    acc[r][0] = fmaf(av, w0, acc[r][0]);
                    acc[r][1] = fmaf(av, w1, acc[r][1]);
                    acc[r][2] = fmaf(av, w2, acc[r][2]);
                }
            }
        }
        #pragma unroll
        for (int r = 0; r < BM; ++r)
            #pragma unroll
            for (int j = 0; j < 3; ++j)
                P[(kg * BM + r) * 384 + c1 + j * 128] = acc[r][j];
    }
    __syncthreads();

    // ---- reduce partials -> X1 (bias + relu) ----
    for (int i = tid; i < BM * 384; i += 1024) {
        const int row = i / 384;
        const int col = i - row * 384;
        float s = b1[col];
        #pragma unroll
        for (int g = 0; g < 8; ++g)
            s += P[(g * BM + row) * 384 + col];
        X1[i] = s > 0.f ? s : 0.f;
    }
    __syncthreads();

    // ---- layer 2: col c1, rows 0..7, k in [kg*48, kg*48+48) ----
    {
        float acc2[BM];
        #pragma unroll
        for (int r = 0; r < BM; ++r) acc2[r] = 0.f;

        const int k0 = kg * 48;
        for (int k = k0; k < k0 + 48; k += 4) {
            float4 x[BM];
            #pragma unroll
            for (int r = 0; r < BM; ++r)
                x[r] = *reinterpret_cast<const float4*>(&X1[r * 384 + k]);
            #pragma unroll
            for (int kk = 0; kk < 4; ++kk) {
                const float w = W2[(size_t)(k + kk) * 128 + c1];
                #pragma unroll
                for (int r = 0; r < BM; ++r)
                    acc2[r] = fmaf(f4get(x[r], kk), w, acc2[r]);
            }
        }
        #pragma unroll
        for (int r = 0; r < BM; ++r)
            P[(kg * BM + r) * 128 + c1] = acc2[r];
    }
    __syncthreads();

    // ---- reduce partials -> X2 (bias + relu) ----
    {
        const int row = tid >> 7;
        const int col = c1;
        float s = b2[col];
        #pragma unroll
        for (int g = 0; g < 8; ++g)
            s += P[(g * BM + row) * 128 + col];
        X2[row * 128 + col] = s > 0.f ? s : 0.f;
    }
    __syncthreads();

    // ---- layer 3: 16 outputs ----
    if (tid < BM * 2) {
        const int r = tid >> 1;
        const int c = tid & 1;
        float sacc = 0.f;
        #pragma unroll 8
        for (int k = 0; k < 128; ++k)
            sacc = fmaf(X2[r * 128 + k], W3[k * 2 + c], sacc);
        out[(row0 + r) * 2 + c] = sacc + b3[c];
    }
}

extern "C" void kernel_launch(void* const* d_in, const int* in_sizes, int n_in,
                              void* d_out, int out_size, void* d_ws, size_t ws_size,
                              hipStream_t stream) {
    const float* hidden = (const float*)d_in[0];
    const int*   seg    = (const int*)d_in[1];
    const float* W1     = (const float*)d_in[2];
    const float* b1     = (const float*)d_in[3];
    const float* W2     = (const float*)d_in[4];
    const float* b2     = (const float*)d_in[5];
    const float* W3     = (const float*)d_in[6];
    const float* b3     = (const float*)d_in[7];
    float* out  = (float*)d_out;
    float* sent = (float*)d_ws;  // BATCH*SMAX*DIM floats = 6 MB

    // bounds scratch: tail of ws if it fits, else reuse d_out (fully
    // overwritten by mlp_kernel before validation; stream-ordered so safe).
    const size_t sent_bytes = (size_t)BATCH * SMAX * DIM * sizeof(float);
    const size_t bounds_bytes = (size_t)BATCH * (SMAX + 1) * sizeof(int);
    int* bounds;
    if (ws_size >= sent_bytes + bounds_bytes)
        bounds = (int*)((char*)d_ws + sent_bytes);
    else
        bounds = (int*)d_out;  // 16 KB >= 8.3 KB needed

    bounds_kernel<<<BATCH, 192, 0, stream>>>(seg, bounds);
    segsum_kernel<<<dim3(SMAX, BATCH), 192, 0, stream>>>(hidden, bounds, sent);
    mlp_kernel<<<(BATCH * SMAX) / BM, 1024, 0, stream>>>(sent, W1, b1, W2, b2, W3, b3, out);
}

// Round 10
// 67.428 us; speedup vs baseline: 1.0818x; 1.0818x over previous
//
#include <hip/hip_runtime.h>

#define BATCH 16
#define TOK   4096
#define DIM   768
#define SMAX  128
#define BM    8     // segments (= MLP rows) per block

__device__ __forceinline__ int lower_bound_i(const int* __restrict__ a, int n, int v) {
    int lo = 0, hi = n;
    while (lo < hi) {
        int m = (lo + hi) >> 1;
        if (a[m] < v) lo = m + 1; else hi = m;
    }
    return lo;
}

__device__ __forceinline__ float f4get(const float4& v, int k) {
    switch (k) {
        case 0: return v.x;
        case 1: return v.y;
        case 2: return v.z;
        default: return v.w;
    }
}

__device__ __forceinline__ void f2acc(float2& a, const float2& v) {
    a.x += v.x; a.y += v.y;
}

// Kernel 0: precompute span boundaries (independent parallel searches).
__global__ __launch_bounds__(192)
void bounds_kernel(const int* __restrict__ seg, int* __restrict__ bounds) {
    const int b = blockIdx.x;
    const int s = threadIdx.x;
    if (s <= SMAX)
        bounds[b * (SMAX + 1) + s] = lower_bound_i(seg + b * TOK, TOK, s);
}

// Fused kernel: phase A sums this block's 8 token-spans straight into the
// LDS A-tile (8 groups x 128 threads, 6 floats/thread, 12-deep pipeline);
// phase B is the k-split MLP (8 kg-groups, weights read once per block).
__global__ __launch_bounds__(1024)
void fused_kernel(const float* __restrict__ hidden,
                  const int* __restrict__ bounds,
                  const float* __restrict__ W1, const float* __restrict__ b1,
                  const float* __restrict__ W2, const float* __restrict__ b2,
                  const float* __restrict__ W3, const float* __restrict__ b3,
                  float* __restrict__ out) {
    __shared__ __align__(16) float A [BM * DIM];        // 24 KB
    __shared__ __align__(16) float X1[BM * 384];        // 12 KB
    __shared__ __align__(16) float X2[BM * 128];        //  4 KB
    __shared__ __align__(16) float P [8 * BM * 384];    // 96 KB

    const int tid  = threadIdx.x;
    const int row0 = blockIdx.x * BM;
    const int b    = row0 / SMAX;
    const int s0   = row0 % SMAX;

    // ================= phase A: segment sums -> A =================
    {
        const int grp  = tid >> 7;        // segment 0..7 within block
        const int lane = tid & 127;       // owns 6 floats: cols lane*6..lane*6+5

        const int lo = bounds[b * (SMAX + 1) + s0 + grp];
        const int hi = bounds[b * (SMAX + 1) + s0 + grp + 1];

        // float2 view: row has 384 float2; this thread's offset = lane*3
        const float2* __restrict__ hp =
            reinterpret_cast<const float2*>(hidden + (size_t)b * TOK * DIM) + lane * 3;

        float2 a0 = make_float2(0.f, 0.f);
        float2 a1 = make_float2(0.f, 0.f);
        float2 a2 = make_float2(0.f, 0.f);

        int t = lo;
        for (; t + 12 <= hi; t += 12) {
            float2 v0[12], v1[12], v2[12];
            #pragma unroll
            for (int u = 0; u < 12; ++u) {
                const float2* p = hp + (size_t)(t + u) * 384;
                v0[u] = p[0]; v1[u] = p[1]; v2[u] = p[2];
            }
            #pragma unroll
            for (int u = 0; u < 12; ++u) {
                f2acc(a0, v0[u]); f2acc(a1, v1[u]); f2acc(a2, v2[u]);
            }
        }
        for (; t + 4 <= hi; t += 4) {
            float2 v0[4], v1[4], v2[4];
            #pragma unroll
            for (int u = 0; u < 4; ++u) {
                const float2* p = hp + (size_t)(t + u) * 384;
                v0[u] = p[0]; v1[u] = p[1]; v2[u] = p[2];
            }
            #pragma unroll
            for (int u = 0; u < 4; ++u) {
                f2acc(a0, v0[u]); f2acc(a1, v1[u]); f2acc(a2, v2[u]);
            }
        }
        for (; t < hi; ++t) {
            const float2* p = hp + (size_t)t * 384;
            f2acc(a0, p[0]); f2acc(a1, p[1]); f2acc(a2, p[2]);
        }

        float2* dA = reinterpret_cast<float2*>(&A[grp * DIM + lane * 6]);
        dA[0] = a0; dA[1] = a1; dA[2] = a2;
    }
    __syncthreads();

    // ================= phase B: MLP (identical to R9) =================
    const int c1 = tid & 127;   // weight column within 128-group
    const int kg = tid >> 7;    // k-slice group 0..7

    // ---- layer 1: cols {c1, c1+128, c1+256}, rows 0..7, k in [kg*96, kg*96+96) ----
    {
        float acc[BM][3];
        #pragma unroll
        for (int r = 0; r < BM; ++r)
            #pragma unroll
            for (int j = 0; j < 3; ++j) acc[r][j] = 0.f;

        const int k0 = kg * 96;
        for (int k = k0; k < k0 + 96; k += 4) {
            float4 a[BM];
            #pragma unroll
            for (int r = 0; r < BM; ++r)
                a[r] = *reinterpret_cast<const float4*>(&A[r * DIM + k]);
            #pragma unroll
            for (int kk = 0; kk < 4; ++kk) {
                const float w0 = W1[(size_t)(k + kk) * 384 + c1];
                const float w1 = W1[(size_t)(k + kk) * 384 + c1 + 128];
                const float w2 = W1[(size_t)(k + kk) * 384 + c1 + 256];
                #pragma unroll
                for (int r = 0; r < BM; ++r) {
                    const float av = f4get(a[r], kk);
                    acc[r][0] = fmaf(av, w0, acc[r][0]);
                    acc[r][1] = fmaf(av, w1, acc[r][1]);
                    acc[r][2] = fmaf(av, w2, acc[r][2]);
                }
            }
        }
        #pragma unroll
        for (int r = 0; r < BM; ++r)
            #pragma unroll
            for (int j = 0; j < 3; ++j)
                P[(kg * BM + r) * 384 + c1 + j * 128] = acc[r][j];
    }
    __syncthreads();

    // ---- reduce partials -> X1 (bias + relu) ----
    for (int i = tid; i < BM * 384; i += 1024) {
        const int row = i / 384;
        const int col = i - row * 384;
        float s = b1[col];
        #pragma unroll
        for (int g = 0; g < 8; ++g)
            s += P[(g * BM + row) * 384 + col];
        X1[i] = s > 0.f ? s : 0.f;
    }
    __syncthreads();

    // ---- layer 2: col c1, rows 0..7, k in [kg*48, kg*48+48) ----
    {
        float acc2[BM];
        #pragma unroll
        for (int r = 0; r < BM; ++r) acc2[r] = 0.f;

        const int k0 = kg * 48;
        for (int k = k0; k < k0 + 48; k += 4) {
            float4 x[BM];
            #pragma unroll
            for (int r = 0; r < BM; ++r)
                x[r] = *reinterpret_cast<const float4*>(&X1[r * 384 + k]);
            #pragma unroll
            for (int kk = 0; kk < 4; ++kk) {
                const float w = W2[(size_t)(k + kk) * 128 + c1];
                #pragma unroll
                for (int r = 0; r < BM; ++r)
                    acc2[r] = fmaf(f4get(x[r], kk), w, acc2[r]);
            }
        }
        #pragma unroll
        for (int r = 0; r < BM; ++r)
            P[(kg * BM + r) * 128 + c1] = acc2[r];
    }
    __syncthreads();

    // ---- reduce partials -> X2 (bias + relu) ----
    {
        const int row = tid >> 7;
        const int col = c1;
        float s = b2[col];
        #pragma unroll
        for (int g = 0; g < 8; ++g)
            s += P[(g * BM + row) * 128 + col];
        X2[row * 128 + col] = s > 0.f ? s : 0.f;
    }
    __syncthreads();

    // ---- layer 3: 16 outputs ----
    if (tid < BM * 2) {
        const int r = tid >> 1;
        const int c = tid & 1;
        float sacc = 0.f;
        #pragma unroll 8
        for (int k = 0; k < 128; ++k)
            sacc = fmaf(X2[r * 128 + k], W3[k * 2 + c], sacc);
        out[(row0 + r) * 2 + c] = sacc + b3[c];
    }
}

extern "C" void kernel_launch(void* const* d_in, const int* in_sizes, int n_in,
                              void* d_out, int out_size, void* d_ws, size_t ws_size,
                              hipStream_t stream) {
    const float* hidden = (const float*)d_in[0];
    const int*   seg    = (const int*)d_in[1];
    const float* W1     = (const float*)d_in[2];
    const float* b1     = (const float*)d_in[3];
    const float* W2     = (const float*)d_in[4];
    const float* b2     = (const float*)d_in[5];
    const float* W3     = (const float*)d_in[6];
    const float* b3     = (const float*)d_in[7];
    float* out  = (float*)d_out;
    int* bounds = (int*)d_ws;   // 16*129*4 = 8.3 KB, ws is ample

    bounds_kernel<<<BATCH, 192, 0, stream>>>(seg, bounds);
    fused_kernel<<<(BATCH * SMAX) / BM, 1024, 0, stream>>>(
        hidden, bounds, W1, b1, W2, b2, W3, b3, out);
}